// Round 1
// baseline (1201.895 us; speedup 1.0000x reference)
//
#include <hip/hip_runtime.h>
#include <hip/hip_bf16.h>

#define T_TOK 4096
#define DM 1024
#define DF 4096
#define NE 8

typedef __attribute__((ext_vector_type(4))) float f32x4;
typedef __attribute__((ext_vector_type(8))) short bf16x8;

// XOR swizzle for [row][64 bf16] row-major LDS tiles (row stride 128B):
// spreads rows 0..7 across 16B slots -> conflict-free-ish ds_read_b128.
#define SWZ(b) ((b) ^ ((((b) >> 7) & 7) << 4))

__device__ inline unsigned short f2bf(float f) {
  union { float f; unsigned u; } a; a.f = f;
  unsigned r = a.u + 0x7fffu + ((a.u >> 16) & 1u);
  return (unsigned short)(r >> 16);
}

// ---------------- router: logits, top-2, renorm weights, counts ----------------
__global__ __launch_bounds__(256) void k_router(const float* __restrict__ x,
    const float* __restrict__ Wr, const float* __restrict__ br,
    int* __restrict__ topi, float* __restrict__ topw, int* __restrict__ counts) {
  int t = blockIdx.x;
  int tid = threadIdx.x;
  const float* xr = x + (size_t)t * DM;
  float acc[NE];
#pragma unroll
  for (int e = 0; e < NE; e++) acc[e] = 0.f;
  for (int d = tid; d < DM; d += 256) {
    float xv = xr[d];
    const float* w = Wr + (size_t)d * NE;
#pragma unroll
    for (int e = 0; e < NE; e++) acc[e] += xv * w[e];
  }
  __shared__ float red[NE][256];
#pragma unroll
  for (int e = 0; e < NE; e++) red[e][tid] = acc[e];
  __syncthreads();
  for (int s = 128; s > 0; s >>= 1) {
    if (tid < s) {
#pragma unroll
      for (int e = 0; e < NE; e++) red[e][tid] += red[e][tid + s];
    }
    __syncthreads();
  }
  if (tid == 0) {
    float l[NE];
#pragma unroll
    for (int e = 0; e < NE; e++) l[e] = red[e][0] + br[e];
    int i0 = 0;
#pragma unroll
    for (int e = 1; e < NE; e++) if (l[e] > l[i0]) i0 = e;
    int i1 = (i0 == 0) ? 1 : 0;
#pragma unroll
    for (int e = 0; e < NE; e++) if (e != i0 && l[e] > l[i1]) i1 = e;
    float w1e = expf(l[i1] - l[i0]);
    float w0 = 1.f / (1.f + w1e);
    topi[2 * t] = i0; topi[2 * t + 1] = i1;
    topw[2 * t] = w0; topw[2 * t + 1] = w1e * w0;
    atomicAdd(&counts[i0], 1);
    atomicAdd(&counts[i1], 1);
  }
}

// ---------------- scan: offsets + cv^2 ----------------
__global__ void k_scan(const int* __restrict__ counts, int* __restrict__ offsets,
                       float* __restrict__ cv2out) {
  if (threadIdx.x == 0) {
    int off = 0;
    float util[NE];
    for (int e = 0; e < NE; e++) { offsets[e] = off; off += counts[e]; }
    offsets[NE] = off;
    float mean = 0.f;
    for (int e = 0; e < NE; e++) { util[e] = (float)counts[e] / (float)(2 * T_TOK); mean += util[e]; }
    mean *= (1.f / NE);
    float var = 0.f;
    for (int e = 0; e < NE; e++) { float d = util[e] - mean; var += d * d; }
    var *= (1.f / (NE - 1));
    float den = mean + 1e-6f;
    *cv2out = var / (den * den);
  }
}

// ---------------- scatter: expert-sorted token lists ----------------
__global__ __launch_bounds__(256) void k_scatter(const int* __restrict__ topi,
    const float* __restrict__ topw, const int* __restrict__ offsets,
    int* __restrict__ cursor, int* __restrict__ perm, float* __restrict__ permw) {
  int t = blockIdx.x * 256 + threadIdx.x;
  if (t >= T_TOK) return;
#pragma unroll
  for (int k = 0; k < 2; k++) {
    int e = topi[2 * t + k];
    int p = atomicAdd(&cursor[e], 1);
    int s = offsets[e] + p;
    perm[s] = t;
    permw[s] = topw[2 * t + k];
  }
}

// ---------------- initout: out[t] = w0*b2[e0] + w1*b2[e1] ----------------
__global__ __launch_bounds__(256) void k_initout(const int* __restrict__ topi,
    const float* __restrict__ topw, const float* __restrict__ b2, float* __restrict__ out) {
  int t = blockIdx.x;
  int i0 = topi[2 * t], i1 = topi[2 * t + 1];
  float w0 = topw[2 * t], w1 = topw[2 * t + 1];
  const f32x4* bb0 = (const f32x4*)(b2 + (size_t)i0 * DM);
  const f32x4* bb1 = (const f32x4*)(b2 + (size_t)i1 * DM);
  f32x4* o = (f32x4*)(out + (size_t)t * DM);
  int tid = threadIdx.x;
  o[tid] = w0 * bb0[tid] + w1 * bb1[tid];
}

// ---------------- gemm1: h = gelu(gather(x) @ W1[e] + b1[e]) -> hb (bf16) ----------------
__global__ __launch_bounds__(256) void k_gemm1(const float* __restrict__ x,
    const float* __restrict__ W1, const float* __restrict__ b1,
    const int* __restrict__ offsets, const int* __restrict__ perm,
    unsigned short* __restrict__ hb) {
  int e = blockIdx.z;
  int roff = offsets[e];
  int nrows = offsets[e + 1] - roff;
  int row_base = blockIdx.y * 128;
  if (row_base >= nrows) return;
  int n0 = blockIdx.x * 128;
  int tid = threadIdx.x;
  int lane = tid & 63;
  int wid = tid >> 6;
  int wm = (wid >> 1) * 64, wn = (wid & 1) * 64;

  __shared__ __align__(16) char smA[16384];
  __shared__ __align__(16) char smB[16384];
  __shared__ int tok_s[128];

  if (tid < 128) {
    int r = row_base + tid;
    tok_s[tid] = (r < nrows) ? perm[roff + r] : -1;
  }
  __syncthreads();

  f32x4 acc[4][4];
#pragma unroll
  for (int m = 0; m < 4; m++)
#pragma unroll
    for (int n = 0; n < 4; n++) acc[m][n] = (f32x4)(0.f);

  const float* W1e = W1 + (size_t)e * DM * DF;

  for (int kk = 0; kk < DM / 64; kk++) {
    int k0 = kk * 64;
    // A stage: gathered x rows, f32 -> bf16
#pragma unroll
    for (int i = 0; i < 8; i++) {
      int q = tid + i * 256;
      int row = q >> 4, c4 = q & 15;
      int tk = tok_s[row];
      float4 v = make_float4(0.f, 0.f, 0.f, 0.f);
      if (tk >= 0) v = *(const float4*)(x + (size_t)tk * DM + k0 + c4 * 4);
      unsigned p0 = (unsigned)f2bf(v.x) | ((unsigned)f2bf(v.y) << 16);
      unsigned p1 = (unsigned)f2bf(v.z) | ((unsigned)f2bf(v.w) << 16);
      int b = row * 128 + c4 * 8;
      *(uint2*)(smA + SWZ(b)) = make_uint2(p0, p1);
    }
    // B stage: W1 tile, in-register 4x4 transpose -> [n][k] layout
#pragma unroll
    for (int i = 0; i < 2; i++) {
      int blk = tid + i * 256;
      int kb = blk >> 5, n4 = blk & 31;
      const float* bp = W1e + (size_t)(k0 + kb * 4) * DF + n0 + n4 * 4;
      float4 r0 = *(const float4*)bp;
      float4 r1 = *(const float4*)(bp + DF);
      float4 r2 = *(const float4*)(bp + 2 * DF);
      float4 r3 = *(const float4*)(bp + 3 * DF);
      float rr[4][4] = {{r0.x, r0.y, r0.z, r0.w}, {r1.x, r1.y, r1.z, r1.w},
                        {r2.x, r2.y, r2.z, r2.w}, {r3.x, r3.y, r3.z, r3.w}};
#pragma unroll
      for (int c = 0; c < 4; c++) {
        unsigned p0 = (unsigned)f2bf(rr[0][c]) | ((unsigned)f2bf(rr[1][c]) << 16);
        unsigned p1 = (unsigned)f2bf(rr[2][c]) | ((unsigned)f2bf(rr[3][c]) << 16);
        int n = n4 * 4 + c;
        int b = n * 128 + kb * 8;
        *(uint2*)(smB + SWZ(b)) = make_uint2(p0, p1);
      }
    }
    __syncthreads();
#pragma unroll
    for (int ks = 0; ks < 2; ks++) {
      bf16x8 af[4], bfr[4];
#pragma unroll
      for (int m = 0; m < 4; m++) {
        int row = wm + m * 16 + (lane & 15);
        int b = row * 128 + ks * 64 + (lane >> 4) * 16;
        af[m] = *(const bf16x8*)(smA + SWZ(b));
      }
#pragma unroll
      for (int n = 0; n < 4; n++) {
        int col = wn + n * 16 + (lane & 15);
        int b = col * 128 + ks * 64 + (lane >> 4) * 16;
        bfr[n] = *(const bf16x8*)(smB + SWZ(b));
      }
#pragma unroll
      for (int m = 0; m < 4; m++)
#pragma unroll
        for (int n = 0; n < 4; n++)
          acc[m][n] = __builtin_amdgcn_mfma_f32_16x16x32_bf16(af[m], bfr[n], acc[m][n], 0, 0, 0);
    }
    __syncthreads();
  }
  // epilogue: +b1, exact gelu, store bf16
#pragma unroll
  for (int n = 0; n < 4; n++) {
    int col = n0 + wn + n * 16 + (lane & 15);
    float b1v = b1[e * DF + col];
#pragma unroll
    for (int m = 0; m < 4; m++) {
      int rbase = wm + m * 16 + ((lane >> 4) << 2);
#pragma unroll
      for (int r = 0; r < 4; r++) {
        int grow = row_base + rbase + r;
        if (grow < nrows) {
          float v = acc[m][n][r] + b1v;
          float g = 0.5f * v * (1.f + erff(v * 0.70710678118f));
          hb[(size_t)(roff + grow) * DF + col] = f2bf(g);
        }
      }
    }
  }
}

// ---------------- gemm2: out += w * (h @ W2[e]) ----------------
__global__ __launch_bounds__(256) void k_gemm2(const unsigned short* __restrict__ hb,
    const float* __restrict__ W2, const int* __restrict__ offsets,
    const int* __restrict__ perm, const float* __restrict__ permw,
    float* __restrict__ out) {
  int e = blockIdx.z;
  int roff = offsets[e];
  int nrows = offsets[e + 1] - roff;
  int row_base = blockIdx.y * 128;
  if (row_base >= nrows) return;
  int n0 = blockIdx.x * 128;
  int tid = threadIdx.x;
  int lane = tid & 63;
  int wid = tid >> 6;
  int wm = (wid >> 1) * 64, wn = (wid & 1) * 64;

  __shared__ __align__(16) char smA[16384];
  __shared__ __align__(16) char smB[16384];
  __shared__ int tok_s[128];
  __shared__ float w_s[128];

  if (tid < 128) {
    int r = row_base + tid;
    bool v = (r < nrows);
    tok_s[tid] = v ? perm[roff + r] : -1;
    w_s[tid] = v ? permw[roff + r] : 0.f;
  }
  __syncthreads();

  f32x4 acc[4][4];
#pragma unroll
  for (int m = 0; m < 4; m++)
#pragma unroll
    for (int n = 0; n < 4; n++) acc[m][n] = (f32x4)(0.f);

  const float* W2e = W2 + (size_t)e * DF * DM;

  for (int kk = 0; kk < DF / 64; kk++) {
    int k0 = kk * 64;
    // A stage: hb rows (already bf16)
#pragma unroll
    for (int i = 0; i < 8; i++) {
      int q = tid + i * 256;
      int row = q >> 4, c4 = q & 15;
      int r = row_base + row;
      uint2 v = make_uint2(0u, 0u);
      if (r < nrows) v = *(const uint2*)(hb + (size_t)(roff + r) * DF + k0 + c4 * 4);
      int b = row * 128 + c4 * 8;
      *(uint2*)(smA + SWZ(b)) = v;
    }
    // B stage: W2 tile transpose
#pragma unroll
    for (int i = 0; i < 2; i++) {
      int blk = tid + i * 256;
      int kb = blk >> 5, n4 = blk & 31;
      const float* bp = W2e + (size_t)(k0 + kb * 4) * DM + n0 + n4 * 4;
      float4 r0 = *(const float4*)bp;
      float4 r1 = *(const float4*)(bp + DM);
      float4 r2 = *(const float4*)(bp + 2 * DM);
      float4 r3 = *(const float4*)(bp + 3 * DM);
      float rr[4][4] = {{r0.x, r0.y, r0.z, r0.w}, {r1.x, r1.y, r1.z, r1.w},
                        {r2.x, r2.y, r2.z, r2.w}, {r3.x, r3.y, r3.z, r3.w}};
#pragma unroll
      for (int c = 0; c < 4; c++) {
        unsigned p0 = (unsigned)f2bf(rr[0][c]) | ((unsigned)f2bf(rr[1][c]) << 16);
        unsigned p1 = (unsigned)f2bf(rr[2][c]) | ((unsigned)f2bf(rr[3][c]) << 16);
        int n = n4 * 4 + c;
        int b = n * 128 + kb * 8;
        *(uint2*)(smB + SWZ(b)) = make_uint2(p0, p1);
      }
    }
    __syncthreads();
#pragma unroll
    for (int ks = 0; ks < 2; ks++) {
      bf16x8 af[4], bfr[4];
#pragma unroll
      for (int m = 0; m < 4; m++) {
        int row = wm + m * 16 + (lane & 15);
        int b = row * 128 + ks * 64 + (lane >> 4) * 16;
        af[m] = *(const bf16x8*)(smA + SWZ(b));
      }
#pragma unroll
      for (int n = 0; n < 4; n++) {
        int col = wn + n * 16 + (lane & 15);
        int b = col * 128 + ks * 64 + (lane >> 4) * 16;
        bfr[n] = *(const bf16x8*)(smB + SWZ(b));
      }
#pragma unroll
      for (int m = 0; m < 4; m++)
#pragma unroll
        for (int n = 0; n < 4; n++)
          acc[m][n] = __builtin_amdgcn_mfma_f32_16x16x32_bf16(af[m], bfr[n], acc[m][n], 0, 0, 0);
    }
    __syncthreads();
  }
  // epilogue: weighted atomic accumulate into out
#pragma unroll
  for (int m = 0; m < 4; m++) {
    int rbase = wm + m * 16 + ((lane >> 4) << 2);
#pragma unroll
    for (int r = 0; r < 4; r++) {
      int lrow = rbase + r;
      int grow = row_base + lrow;
      if (grow < nrows) {
        int t = tok_s[lrow];
        float w = w_s[lrow];
#pragma unroll
        for (int n = 0; n < 4; n++) {
          int col = n0 + wn + n * 16 + (lane & 15);
          atomicAdd(out + (size_t)t * DM + col, w * acc[m][n][r]);
        }
      }
    }
  }
}

extern "C" void kernel_launch(void* const* d_in, const int* in_sizes, int n_in,
                              void* d_out, int out_size, void* d_ws, size_t ws_size,
                              hipStream_t stream) {
  const float* x  = (const float*)d_in[0];
  const float* Wr = (const float*)d_in[1];
  const float* br = (const float*)d_in[2];
  const float* W1 = (const float*)d_in[3];
  const float* b1 = (const float*)d_in[4];
  const float* W2 = (const float*)d_in[5];
  const float* b2 = (const float*)d_in[6];
  float* out = (float*)d_out;

  char* ws = (char*)d_ws;
  int*   counts  = (int*)(ws + 0);
  int*   cursor  = (int*)(ws + 64);
  int*   offsets = (int*)(ws + 128);
  int*   topi    = (int*)(ws + 256);
  float* topw    = (float*)(ws + 256 + 32768);
  int*   perm    = (int*)(ws + 256 + 65536);
  float* permw   = (float*)(ws + 256 + 98304);
  unsigned short* hb = (unsigned short*)(ws + 131328);  // 8192 x 4096 bf16 = 64 MB

  hipMemsetAsync(ws, 0, 256, stream);  // counts, cursor, offsets

  k_router<<<T_TOK, 256, 0, stream>>>(x, Wr, br, topi, topw, counts);
  k_scan<<<1, 64, 0, stream>>>(counts, offsets, out + (size_t)T_TOK * DM);
  k_scatter<<<16, 256, 0, stream>>>(topi, topw, offsets, cursor, perm, permw);
  k_initout<<<T_TOK, 256, 0, stream>>>(topi, topw, b2, out);
  k_gemm1<<<dim3(32, 32, 8), 256, 0, stream>>>(x, W1, b1, offsets, perm, hb);
  k_gemm2<<<dim3(8, 32, 8), 256, 0, stream>>>(hb, W2, offsets, perm, permw, out);
}

// Round 3
// 803.185 us; speedup vs baseline: 1.4964x; 1.4964x over previous
//
#include <hip/hip_runtime.h>
#include <hip/hip_bf16.h>

#define T_TOK 4096
#define DM 1024
#define DF 4096
#define NE 8

typedef __attribute__((ext_vector_type(4))) float f32x4;
typedef __attribute__((ext_vector_type(8))) short bf16x8;

// Swizzle 16B-granule index (bits 4-6) with (row&7)^((row>>3)&7); row stride = 128B.
// Reads of 16 consecutive rows: conflict-free. Writes at row stride 4: conflict-free.
__device__ inline int swz(int b) { return b ^ ((((b >> 7) ^ (b >> 10)) & 7) << 4); }

__device__ inline unsigned short f2bf(float f) {
  union { float f; unsigned u; } a; a.f = f;
  unsigned r = a.u + 0x7fffu + ((a.u >> 16) & 1u);
  return (unsigned short)(r >> 16);
}
__device__ inline unsigned pk(float lo, float hi) {
  return (unsigned)f2bf(lo) | ((unsigned)f2bf(hi) << 16);
}
__device__ inline float bf2f(unsigned short u) {
  union { unsigned u; float f; } a; a.u = ((unsigned)u) << 16; return a.f;
}

// ---------------- router ----------------
__global__ __launch_bounds__(256) void k_router(const float* __restrict__ x,
    const float* __restrict__ Wr, const float* __restrict__ br,
    int* __restrict__ topi, float* __restrict__ topw, int* __restrict__ counts) {
  int t = blockIdx.x;
  int tid = threadIdx.x;
  const float* xr = x + (size_t)t * DM;
  float acc[NE];
#pragma unroll
  for (int e = 0; e < NE; e++) acc[e] = 0.f;
  for (int d = tid; d < DM; d += 256) {
    float xv = xr[d];
    const float* w = Wr + (size_t)d * NE;
#pragma unroll
    for (int e = 0; e < NE; e++) acc[e] += xv * w[e];
  }
  __shared__ float red[NE][256];
#pragma unroll
  for (int e = 0; e < NE; e++) red[e][tid] = acc[e];
  __syncthreads();
  for (int s = 128; s > 0; s >>= 1) {
    if (tid < s) {
#pragma unroll
      for (int e = 0; e < NE; e++) red[e][tid] += red[e][tid + s];
    }
    __syncthreads();
  }
  if (tid == 0) {
    float l[NE];
#pragma unroll
    for (int e = 0; e < NE; e++) l[e] = red[e][0] + br[e];
    int i0 = 0;
#pragma unroll
    for (int e = 1; e < NE; e++) if (l[e] > l[i0]) i0 = e;
    int i1 = (i0 == 0) ? 1 : 0;
#pragma unroll
    for (int e = 0; e < NE; e++) if (e != i0 && l[e] > l[i1]) i1 = e;
    float w1e = expf(l[i1] - l[i0]);
    float w0 = 1.f / (1.f + w1e);
    topi[2 * t] = i0; topi[2 * t + 1] = i1;
    topw[2 * t] = w0; topw[2 * t + 1] = w1e * w0;
    atomicAdd(&counts[i0], 1);
    atomicAdd(&counts[i1], 1);
  }
}

// ---------------- scan: offsets + cv^2 ----------------
__global__ void k_scan(const int* __restrict__ counts, int* __restrict__ offsets,
                       float* __restrict__ cv2out) {
  if (threadIdx.x == 0) {
    int off = 0;
    float util[NE];
    for (int e = 0; e < NE; e++) { offsets[e] = off; off += counts[e]; }
    offsets[NE] = off;
    float mean = 0.f;
    for (int e = 0; e < NE; e++) { util[e] = (float)counts[e] / (float)(2 * T_TOK); mean += util[e]; }
    mean *= (1.f / NE);
    float var = 0.f;
    for (int e = 0; e < NE; e++) { float d = util[e] - mean; var += d * d; }
    var *= (1.f / (NE - 1));
    float den = mean + 1e-6f;
    *cv2out = var / (den * den);
  }
}

// ---------------- scatter ----------------
__global__ __launch_bounds__(256) void k_scatter(const int* __restrict__ topi,
    const float* __restrict__ topw, const int* __restrict__ offsets,
    int* __restrict__ cursor, int* __restrict__ perm, float* __restrict__ permw,
    int* __restrict__ tslot) {
  int t = blockIdx.x * 256 + threadIdx.x;
  if (t >= T_TOK) return;
#pragma unroll
  for (int k = 0; k < 2; k++) {
    int e = topi[2 * t + k];
    int p = atomicAdd(&cursor[e], 1);
    int s = offsets[e] + p;
    perm[s] = t;
    permw[s] = topw[2 * t + k];
    tslot[2 * t + k] = s;
  }
}

// ---------------- gemm1: hb = gelu(gather(x) @ W1[e] + b1[e]) ----------------
__global__ __launch_bounds__(256) void k_gemm1(const float* __restrict__ x,
    const float* __restrict__ W1, const float* __restrict__ b1,
    const int* __restrict__ offsets, const int* __restrict__ perm,
    unsigned short* __restrict__ hb) {
  int e = blockIdx.z;
  int roff = offsets[e];
  int nrows = offsets[e + 1] - roff;
  int row_base = blockIdx.y * 128;
  if (row_base >= nrows) return;
  int n0 = blockIdx.x * 128;
  int tid = threadIdx.x, lane = tid & 63, wid = tid >> 6;
  int wm = (wid >> 1) * 64, wn = (wid & 1) * 64;

  __shared__ __align__(16) char smA[2][16384];
  __shared__ __align__(16) char smB[2][16384];
  __shared__ int tok_s[128];
  if (tid < 128) { int r = row_base + tid; tok_s[tid] = (r < nrows) ? perm[roff + r] : -1; }
  __syncthreads();

  const float* W1e = W1 + (size_t)e * DM * DF;

  f32x4 acc[4][4];
#pragma unroll
  for (int m = 0; m < 4; m++)
#pragma unroll
    for (int n = 0; n < 4; n++) acc[m][n] = (f32x4)(0.f);

  float4 arA[4][2];
  float4 brB[8];
  int aRow[4], aG[4];
#pragma unroll
  for (int i = 0; i < 4; i++) { int q = i * 256 + tid; aRow[i] = q >> 3; aG[i] = q & 7; }
  int bn4 = tid & 31, bk8 = tid >> 5;

  auto STAGE = [&](int kk) {
    int k0 = kk * 64;
#pragma unroll
    for (int i = 0; i < 4; i++) {
      int tk = tok_s[aRow[i]];
      if (tk >= 0) {
        const float* p = x + (size_t)tk * DM + k0 + aG[i] * 8;
        arA[i][0] = *(const float4*)p;
        arA[i][1] = *(const float4*)(p + 4);
      } else {
        arA[i][0] = make_float4(0, 0, 0, 0);
        arA[i][1] = make_float4(0, 0, 0, 0);
      }
    }
    const float* bp = W1e + (size_t)(k0 + bk8 * 8) * DF + n0 + bn4 * 4;
#pragma unroll
    for (int j = 0; j < 8; j++) brB[j] = *(const float4*)(bp + (size_t)j * DF);
  };
  auto WRITE = [&](int p) {
#pragma unroll
    for (int i = 0; i < 4; i++) {
      uint4 v;
      v.x = pk(arA[i][0].x, arA[i][0].y);
      v.y = pk(arA[i][0].z, arA[i][0].w);
      v.z = pk(arA[i][1].x, arA[i][1].y);
      v.w = pk(arA[i][1].z, arA[i][1].w);
      *(uint4*)(smA[p] + swz(aRow[i] * 128 + aG[i] * 16)) = v;
    }
#pragma unroll
    for (int c = 0; c < 4; c++) {
      uint4 v;
      v.x = pk(brB[0][c], brB[1][c]);
      v.y = pk(brB[2][c], brB[3][c]);
      v.z = pk(brB[4][c], brB[5][c]);
      v.w = pk(brB[6][c], brB[7][c]);
      int row = bn4 * 4 + c;
      *(uint4*)(smB[p] + swz(row * 128 + bk8 * 16)) = v;
    }
  };
  auto COMPUTE = [&](int p) {
#pragma unroll
    for (int ks = 0; ks < 2; ks++) {
      bf16x8 af[4], bfr[4];
#pragma unroll
      for (int m = 0; m < 4; m++) {
        int row = wm + m * 16 + (lane & 15);
        af[m] = *(const bf16x8*)(smA[p] + swz(row * 128 + ks * 64 + (lane >> 4) * 16));
      }
#pragma unroll
      for (int n = 0; n < 4; n++) {
        int col = wn + n * 16 + (lane & 15);
        bfr[n] = *(const bf16x8*)(smB[p] + swz(col * 128 + ks * 64 + (lane >> 4) * 16));
      }
#pragma unroll
      for (int m = 0; m < 4; m++)
#pragma unroll
        for (int n = 0; n < 4; n++)
          acc[m][n] = __builtin_amdgcn_mfma_f32_16x16x32_bf16(af[m], bfr[n], acc[m][n], 0, 0, 0);
    }
  };

  STAGE(0); WRITE(0); __syncthreads();
  for (int kk = 0; kk < DM / 64; kk++) {
    if (kk < DM / 64 - 1) STAGE(kk + 1);
    COMPUTE(kk & 1);
    if (kk < DM / 64 - 1) WRITE((kk + 1) & 1);
    __syncthreads();
  }

#pragma unroll
  for (int n = 0; n < 4; n++) {
    int col = n0 + wn + n * 16 + (lane & 15);
    float b1v = b1[e * DF + col];
#pragma unroll
    for (int m = 0; m < 4; m++) {
      int rbase = wm + m * 16 + ((lane >> 4) << 2);
#pragma unroll
      for (int r = 0; r < 4; r++) {
        int grow = row_base + rbase + r;
        if (grow < nrows) {
          float v = acc[m][n][r] + b1v;
          float g = 0.5f * v * (1.f + erff(v * 0.70710678118f));
          hb[(size_t)(roff + grow) * DF + col] = f2bf(g);
        }
      }
    }
  }
}

// ---------------- gemm2: y[slot] = hb[slot] @ W2[e]  (bf16, no weights) ----------------
__global__ __launch_bounds__(256) void k_gemm2(const unsigned short* __restrict__ hb,
    const float* __restrict__ W2, const int* __restrict__ offsets,
    unsigned short* __restrict__ y) {
  int e = blockIdx.z;
  int roff = offsets[e];
  int nrows = offsets[e + 1] - roff;
  int row_base = blockIdx.y * 128;
  if (row_base >= nrows) return;
  int n0 = blockIdx.x * 128;
  int tid = threadIdx.x, lane = tid & 63, wid = tid >> 6;
  int wm = (wid >> 1) * 64, wn = (wid & 1) * 64;

  __shared__ __align__(16) char smA[2][16384];
  __shared__ __align__(16) char smB[2][16384];

  const float* W2e = W2 + (size_t)e * DF * DM;

  f32x4 acc[4][4];
#pragma unroll
  for (int m = 0; m < 4; m++)
#pragma unroll
    for (int n = 0; n < 4; n++) acc[m][n] = (f32x4)(0.f);

  uint4 arA[4];
  float4 brB[8];
  int aRow[4], aG[4];
#pragma unroll
  for (int i = 0; i < 4; i++) { int q = i * 256 + tid; aRow[i] = q >> 3; aG[i] = q & 7; }
  int bn4 = tid & 31, bk8 = tid >> 5;

  auto STAGE = [&](int kk) {
    int k0 = kk * 64;
#pragma unroll
    for (int i = 0; i < 4; i++) {
      int r = row_base + aRow[i];
      if (r < nrows)
        arA[i] = *(const uint4*)(hb + (size_t)(roff + r) * DF + k0 + aG[i] * 8);
      else
        arA[i] = make_uint4(0, 0, 0, 0);
    }
    const float* bp = W2e + (size_t)(k0 + bk8 * 8) * DM + n0 + bn4 * 4;
#pragma unroll
    for (int j = 0; j < 8; j++) brB[j] = *(const float4*)(bp + (size_t)j * DM);
  };
  auto WRITE = [&](int p) {
#pragma unroll
    for (int i = 0; i < 4; i++)
      *(uint4*)(smA[p] + swz(aRow[i] * 128 + aG[i] * 16)) = arA[i];
#pragma unroll
    for (int c = 0; c < 4; c++) {
      uint4 v;
      v.x = pk(brB[0][c], brB[1][c]);
      v.y = pk(brB[2][c], brB[3][c]);
      v.z = pk(brB[4][c], brB[5][c]);
      v.w = pk(brB[6][c], brB[7][c]);
      int row = bn4 * 4 + c;
      *(uint4*)(smB[p] + swz(row * 128 + bk8 * 16)) = v;
    }
  };
  auto COMPUTE = [&](int p) {
#pragma unroll
    for (int ks = 0; ks < 2; ks++) {
      bf16x8 af[4], bfr[4];
#pragma unroll
      for (int m = 0; m < 4; m++) {
        int row = wm + m * 16 + (lane & 15);
        af[m] = *(const bf16x8*)(smA[p] + swz(row * 128 + ks * 64 + (lane >> 4) * 16));
      }
#pragma unroll
      for (int n = 0; n < 4; n++) {
        int col = wn + n * 16 + (lane & 15);
        bfr[n] = *(const bf16x8*)(smB[p] + swz(col * 128 + ks * 64 + (lane >> 4) * 16));
      }
#pragma unroll
      for (int m = 0; m < 4; m++)
#pragma unroll
        for (int n = 0; n < 4; n++)
          acc[m][n] = __builtin_amdgcn_mfma_f32_16x16x32_bf16(af[m], bfr[n], acc[m][n], 0, 0, 0);
    }
  };

  STAGE(0); WRITE(0); __syncthreads();
  for (int kk = 0; kk < DF / 64; kk++) {
    if (kk < DF / 64 - 1) STAGE(kk + 1);
    COMPUTE(kk & 1);
    if (kk < DF / 64 - 1) WRITE((kk + 1) & 1);
    __syncthreads();
  }

#pragma unroll
  for (int m = 0; m < 4; m++) {
    int rbase = wm + m * 16 + ((lane >> 4) << 2);
#pragma unroll
    for (int r = 0; r < 4; r++) {
      int grow = row_base + rbase + r;
      if (grow < nrows) {
#pragma unroll
        for (int n = 0; n < 4; n++) {
          int col = n0 + wn + n * 16 + (lane & 15);
          y[(size_t)(roff + grow) * DM + col] = f2bf(acc[m][n][r]);
        }
      }
    }
  }
}

// ---------------- combine: out[t] = sum_k w_k * (y[slot_k] + b2[e_k]) ----------------
__global__ __launch_bounds__(256) void k_combine(const int* __restrict__ topi,
    const float* __restrict__ topw, const int* __restrict__ tslot,
    const unsigned short* __restrict__ y, const float* __restrict__ b2,
    float* __restrict__ out) {
  int t = blockIdx.x, tid = threadIdx.x;
  int s0 = tslot[2 * t], s1 = tslot[2 * t + 1];
  int e0 = topi[2 * t], e1 = topi[2 * t + 1];
  float w0 = topw[2 * t], w1 = topw[2 * t + 1];
  int d = tid * 4;
  uint2 ya = *(const uint2*)(y + (size_t)s0 * DM + d);
  uint2 yb = *(const uint2*)(y + (size_t)s1 * DM + d);
  f32x4 bb0 = *(const f32x4*)(b2 + (size_t)e0 * DM + d);
  f32x4 bb1 = *(const f32x4*)(b2 + (size_t)e1 * DM + d);
  f32x4 r;
  r[0] = w0 * (bf2f((unsigned short)(ya.x & 0xffff)) + bb0[0]) + w1 * (bf2f((unsigned short)(yb.x & 0xffff)) + bb1[0]);
  r[1] = w0 * (bf2f((unsigned short)(ya.x >> 16)) + bb0[1]) + w1 * (bf2f((unsigned short)(yb.x >> 16)) + bb1[1]);
  r[2] = w0 * (bf2f((unsigned short)(ya.y & 0xffff)) + bb0[2]) + w1 * (bf2f((unsigned short)(yb.y & 0xffff)) + bb1[2]);
  r[3] = w0 * (bf2f((unsigned short)(ya.y >> 16)) + bb0[3]) + w1 * (bf2f((unsigned short)(yb.y >> 16)) + bb1[3]);
  *(f32x4*)(out + (size_t)t * DM + d) = r;
}

extern "C" void kernel_launch(void* const* d_in, const int* in_sizes, int n_in,
                              void* d_out, int out_size, void* d_ws, size_t ws_size,
                              hipStream_t stream) {
  const float* x  = (const float*)d_in[0];
  const float* Wr = (const float*)d_in[1];
  const float* br = (const float*)d_in[2];
  const float* W1 = (const float*)d_in[3];
  const float* b1 = (const float*)d_in[4];
  const float* W2 = (const float*)d_in[5];
  const float* b2 = (const float*)d_in[6];
  float* out = (float*)d_out;

  char* ws = (char*)d_ws;
  int*   counts  = (int*)(ws + 0);
  int*   cursor  = (int*)(ws + 64);
  int*   offsets = (int*)(ws + 128);
  int*   topi    = (int*)(ws + 256);
  float* topw    = (float*)(ws + 33024);
  int*   perm    = (int*)(ws + 65792);
  float* permw   = (float*)(ws + 98560);
  int*   tslot   = (int*)(ws + 131328);
  unsigned short* hb = (unsigned short*)(ws + 164096);              // 8192x4096 bf16 = 64 MB
  unsigned short* y  = (unsigned short*)(ws + 164096 + 67108864);   // 8192x1024 bf16 = 16.8 MB

  hipMemsetAsync(ws, 0, 256, stream);  // counts, cursor

  k_router<<<T_TOK, 256, 0, stream>>>(x, Wr, br, topi, topw, counts);
  k_scan<<<1, 64, 0, stream>>>(counts, offsets, out + (size_t)T_TOK * DM);
  k_scatter<<<16, 256, 0, stream>>>(topi, topw, offsets, cursor, perm, permw, tslot);
  k_gemm1<<<dim3(32, 32, 8), 256, 0, stream>>>(x, W1, b1, offsets, perm, hb);
  k_gemm2<<<dim3(8, 32, 8), 256, 0, stream>>>(hb, W2, offsets, y);
  k_combine<<<T_TOK, 256, 0, stream>>>(topi, topw, tslot, y, b2, out);
}

// Round 6
// 784.241 us; speedup vs baseline: 1.5326x; 1.0242x over previous
//
#include <hip/hip_runtime.h>
#include <hip/hip_bf16.h>

#define T_TOK 4096
#define DM 1024
#define DF 4096
#define NE 8

typedef __attribute__((ext_vector_type(4))) float f32x4;
typedef __attribute__((ext_vector_type(8))) short bf16x8;

__device__ inline unsigned short f2bf(float f) {
  union { float f; unsigned u; } a; a.f = f;
  unsigned r = a.u + 0x7fffu + ((a.u >> 16) & 1u);
  return (unsigned short)(r >> 16);
}
__device__ inline unsigned pk(float lo, float hi) {
  return (unsigned)f2bf(lo) | ((unsigned)f2bf(hi) << 16);
}
__device__ inline float bf2f(unsigned short u) {
  union { unsigned u; float f; } a; a.u = ((unsigned)u) << 16; return a.f;
}

// async global->LDS, 16B per lane. LDS dest must be (wave-uniform base + lane*16).
__device__ inline void gload16(const void* g, void* l) {
  __builtin_amdgcn_global_load_lds(
      (const __attribute__((address_space(1))) unsigned int*)g,
      (__attribute__((address_space(3))) unsigned int*)l, 16, 0, 0);
}

// ---------------- router ----------------
__global__ __launch_bounds__(256) void k_router(const float* __restrict__ x,
    const float* __restrict__ Wr, const float* __restrict__ br,
    int* __restrict__ topi, float* __restrict__ topw, int* __restrict__ counts) {
  int t = blockIdx.x;
  int tid = threadIdx.x;
  const float* xr = x + (size_t)t * DM;
  float acc[NE];
#pragma unroll
  for (int e = 0; e < NE; e++) acc[e] = 0.f;
  for (int d = tid; d < DM; d += 256) {
    float xv = xr[d];
    const float* w = Wr + (size_t)d * NE;
#pragma unroll
    for (int e = 0; e < NE; e++) acc[e] += xv * w[e];
  }
  __shared__ float red[NE][256];
#pragma unroll
  for (int e = 0; e < NE; e++) red[e][tid] = acc[e];
  __syncthreads();
  for (int s = 128; s > 0; s >>= 1) {
    if (tid < s) {
#pragma unroll
      for (int e = 0; e < NE; e++) red[e][tid] += red[e][tid + s];
    }
    __syncthreads();
  }
  if (tid == 0) {
    float l[NE];
#pragma unroll
    for (int e = 0; e < NE; e++) l[e] = red[e][0] + br[e];
    int i0 = 0;
#pragma unroll
    for (int e = 1; e < NE; e++) if (l[e] > l[i0]) i0 = e;
    int i1 = (i0 == 0) ? 1 : 0;
#pragma unroll
    for (int e = 0; e < NE; e++) if (e != i0 && l[e] > l[i1]) i1 = e;
    float w1e = expf(l[i1] - l[i0]);
    float w0 = 1.f / (1.f + w1e);
    topi[2 * t] = i0; topi[2 * t + 1] = i1;
    topw[2 * t] = w0; topw[2 * t + 1] = w1e * w0;
    atomicAdd(&counts[i0], 1);
    atomicAdd(&counts[i1], 1);
  }
}

// ---------------- scan: offsets + cv^2 ----------------
__global__ void k_scan(const int* __restrict__ counts, int* __restrict__ offsets,
                       float* __restrict__ cv2out) {
  if (threadIdx.x == 0) {
    int off = 0;
    float util[NE];
    for (int e = 0; e < NE; e++) { offsets[e] = off; off += counts[e]; }
    offsets[NE] = off;
    float mean = 0.f;
    for (int e = 0; e < NE; e++) { util[e] = (float)counts[e] / (float)(2 * T_TOK); mean += util[e]; }
    mean *= (1.f / NE);
    float var = 0.f;
    for (int e = 0; e < NE; e++) { float d = util[e] - mean; var += d * d; }
    var *= (1.f / (NE - 1));
    float den = mean + 1e-6f;
    *cv2out = var / (den * den);
  }
}

// ---------------- scatter ----------------
__global__ __launch_bounds__(256) void k_scatter(const int* __restrict__ topi,
    const int* __restrict__ offsets, int* __restrict__ cursor,
    int* __restrict__ perm, int* __restrict__ tslot) {
  int t = blockIdx.x * 256 + threadIdx.x;
  if (t >= T_TOK) return;
#pragma unroll
  for (int k = 0; k < 2; k++) {
    int e = topi[2 * t + k];
    int p = atomicAdd(&cursor[e], 1);
    int s = offsets[e] + p;
    perm[s] = t;
    tslot[2 * t + k] = s;
  }
}

// ---------------- cvtx: x f32 -> bf16 ----------------
__global__ __launch_bounds__(256) void k_cvtx(const float* __restrict__ x,
    unsigned short* __restrict__ xc) {
  size_t i = ((size_t)blockIdx.x * 256 + threadIdx.x) * 8;
  f32x4 a = *(const f32x4*)(x + i);
  f32x4 b = *(const f32x4*)(x + i + 4);
  uint4 v;
  v.x = pk(a[0], a[1]); v.y = pk(a[2], a[3]);
  v.z = pk(b[0], b[1]); v.w = pk(b[2], b[3]);
  *(uint4*)(xc + i) = v;
}

// ---------------- cvtT: W [e][K][N] f32 -> Wt [e][N][K] bf16 (transpose+convert) ---------
__global__ __launch_bounds__(256) void k_cvtT(const float* __restrict__ src,
    unsigned short* __restrict__ dst, int K, int N) {
  int e = blockIdx.z;
  int n0 = blockIdx.x * 64, k0 = blockIdx.y * 64;
  int tid = threadIdx.x;
  __shared__ float tile[64][65];
  const float* s = src + (size_t)e * K * N + (size_t)k0 * N + n0;
  int r0 = tid >> 4, c4 = (tid & 15) * 4;
#pragma unroll
  for (int i = 0; i < 4; i++) {
    int r = r0 + i * 16;
    float4 v = *(const float4*)(s + (size_t)r * N + c4);
    tile[r][c4] = v.x; tile[r][c4 + 1] = v.y; tile[r][c4 + 2] = v.z; tile[r][c4 + 3] = v.w;
  }
  __syncthreads();
  int n = tid >> 2, kc = (tid & 3) * 16;
  unsigned o[8];
#pragma unroll
  for (int j = 0; j < 8; j++)
    o[j] = pk(tile[kc + 2 * j][n], tile[kc + 2 * j + 1][n]);
  unsigned short* dp = dst + (size_t)e * N * K + (size_t)(n0 + n) * K + k0 + kc;
  *(uint4*)dp = make_uint4(o[0], o[1], o[2], o[3]);
  *(uint4*)(dp + 8) = make_uint4(o[4], o[5], o[6], o[7]);
}

// ---------------- gemm1: hb = gelu(gather(xc) @ W1t^T + b1) ----------------
// A: gathered xc rows (bf16). B: W1t [e][n][k] bf16. Both staged by global_load_lds
// (linear LDS dest, inverse-swizzled global src); ds_read applies the same XOR.
__global__ __launch_bounds__(256) void k_gemm1(const unsigned short* __restrict__ xc,
    const unsigned short* __restrict__ W1t, const float* __restrict__ b1,
    const int* __restrict__ offsets, const int* __restrict__ perm,
    unsigned short* __restrict__ hb) {
  int e = blockIdx.z;
  int roff = offsets[e];
  int nrows = offsets[e + 1] - roff;
  int row_base = blockIdx.y * 128;
  if (row_base >= nrows) return;
  int n0 = blockIdx.x * 128;
  int tid = threadIdx.x, lane = tid & 63, wid = tid >> 6;
  int wm = (wid >> 1) * 64, wn = (wid & 1) * 64;

  __shared__ __align__(16) unsigned short smA[128 * 64];
  __shared__ __align__(16) unsigned short smB[128 * 64];
  __shared__ int tok_s[128];
  if (tid < 128) {
    int r = row_base + tid;
    tok_s[tid] = (r < nrows) ? perm[roff + r] : 0;
  }
  __syncthreads();

  f32x4 acc[4][4];
#pragma unroll
  for (int m = 0; m < 4; m++)
#pragma unroll
    for (int n = 0; n < 4; n++) acc[m][n] = (f32x4)(0.f);

  const unsigned short* Bbase = W1t + (size_t)e * DF * DM + (size_t)n0 * DM;

  const unsigned short* aP[4];
  const unsigned short* bP[4];
  unsigned short* lA[4];
  unsigned short* lB[4];
#pragma unroll
  for (int i = 0; i < 4; i++) {
    int c = tid + i * 256;
    int row = c >> 3;
    int o = ((c & 7) ^ (row & 7)) * 8;   // inverse of read-side XOR swizzle
    aP[i] = xc + (size_t)tok_s[row] * DM + o;
    bP[i] = Bbase + (size_t)row * DM + o;
    lA[i] = smA + c * 8;
    lB[i] = smB + c * 8;
  }

  for (int kk = 0; kk < DM / 64; kk++) {
    int k0 = kk * 64;
#pragma unroll
    for (int i = 0; i < 4; i++) {
      gload16(aP[i] + k0, lA[i]);
      gload16(bP[i] + k0, lB[i]);
    }
    __syncthreads();   // drains vmcnt: LDS tiles ready
#pragma unroll
    for (int ks = 0; ks < 2; ks++) {
      bf16x8 af[4], bfr[4];
#pragma unroll
      for (int m = 0; m < 4; m++) {
        int row = wm + m * 16 + (lane & 15);
        int col = ks * 64 + (lane >> 4) * 16;
        af[m] = *(const bf16x8*)((const char*)smA + row * 128 + (col ^ ((row & 7) << 4)));
      }
#pragma unroll
      for (int n = 0; n < 4; n++) {
        int row = wn + n * 16 + (lane & 15);
        int col = ks * 64 + (lane >> 4) * 16;
        bfr[n] = *(const bf16x8*)((const char*)smB + row * 128 + (col ^ ((row & 7) << 4)));
      }
#pragma unroll
      for (int m = 0; m < 4; m++)
#pragma unroll
        for (int n = 0; n < 4; n++)
          acc[m][n] = __builtin_amdgcn_mfma_f32_16x16x32_bf16(af[m], bfr[n], acc[m][n], 0, 0, 0);
    }
    __syncthreads();   // all reads done before next DMA overwrites
  }

#pragma unroll
  for (int n = 0; n < 4; n++) {
    int col = n0 + wn + n * 16 + (lane & 15);
    float b1v = b1[e * DF + col];
#pragma unroll
    for (int m = 0; m < 4; m++) {
      int rbase = wm + m * 16 + ((lane >> 4) << 2);
#pragma unroll
      for (int r = 0; r < 4; r++) {
        int grow = row_base + rbase + r;
        if (grow < nrows) {
          float v = acc[m][n][r] + b1v;
          float g = 0.5f * v * (1.f + erff(v * 0.70710678118f));
          hb[(size_t)(roff + grow) * DF + col] = f2bf(g);
        }
      }
    }
  }
}

// ---------------- gemm2: y[slot] = hb[slot] @ W2t^T ----------------
__global__ __launch_bounds__(256) void k_gemm2(const unsigned short* __restrict__ hb,
    const unsigned short* __restrict__ W2t, const int* __restrict__ offsets,
    unsigned short* __restrict__ y) {
  int e = blockIdx.z;
  int roff = offsets[e];
  int nrows = offsets[e + 1] - roff;
  int row_base = blockIdx.y * 128;
  if (row_base >= nrows) return;
  int n0 = blockIdx.x * 128;
  int tid = threadIdx.x, lane = tid & 63, wid = tid >> 6;
  int wm = (wid >> 1) * 64, wn = (wid & 1) * 64;

  __shared__ __align__(16) unsigned short smA[128 * 64];
  __shared__ __align__(16) unsigned short smB[128 * 64];

  f32x4 acc[4][4];
#pragma unroll
  for (int m = 0; m < 4; m++)
#pragma unroll
    for (int n = 0; n < 4; n++) acc[m][n] = (f32x4)(0.f);

  const unsigned short* Abase = hb + (size_t)(roff + row_base) * DF;
  const unsigned short* Bbase = W2t + (size_t)e * DM * DF + (size_t)n0 * DF;

  const unsigned short* aP[4];
  const unsigned short* bP[4];
  unsigned short* lA[4];
  unsigned short* lB[4];
#pragma unroll
  for (int i = 0; i < 4; i++) {
    int c = tid + i * 256;
    int row = c >> 3;
    int o = ((c & 7) ^ (row & 7)) * 8;
    aP[i] = Abase + (size_t)row * DF + o;   // rows >= nrows read garbage; discarded
    bP[i] = Bbase + (size_t)row * DF + o;
    lA[i] = smA + c * 8;
    lB[i] = smB + c * 8;
  }

  for (int kk = 0; kk < DF / 64; kk++) {
    int k0 = kk * 64;
#pragma unroll
    for (int i = 0; i < 4; i++) {
      gload16(aP[i] + k0, lA[i]);
      gload16(bP[i] + k0, lB[i]);
    }
    __syncthreads();
#pragma unroll
    for (int ks = 0; ks < 2; ks++) {
      bf16x8 af[4], bfr[4];
#pragma unroll
      for (int m = 0; m < 4; m++) {
        int row = wm + m * 16 + (lane & 15);
        int col = ks * 64 + (lane >> 4) * 16;
        af[m] = *(const bf16x8*)((const char*)smA + row * 128 + (col ^ ((row & 7) << 4)));
      }
#pragma unroll
      for (int n = 0; n < 4; n++) {
        int row = wn + n * 16 + (lane & 15);
        int col = ks * 64 + (lane >> 4) * 16;
        bfr[n] = *(const bf16x8*)((const char*)smB + row * 128 + (col ^ ((row & 7) << 4)));
      }
#pragma unroll
      for (int m = 0; m < 4; m++)
#pragma unroll
        for (int n = 0; n < 4; n++)
          acc[m][n] = __builtin_amdgcn_mfma_f32_16x16x32_bf16(af[m], bfr[n], acc[m][n], 0, 0, 0);
    }
    __syncthreads();
  }

#pragma unroll
  for (int m = 0; m < 4; m++) {
    int rbase = wm + m * 16 + ((lane >> 4) << 2);
#pragma unroll
    for (int r = 0; r < 4; r++) {
      int grow = row_base + rbase + r;
      if (grow < nrows) {
#pragma unroll
        for (int n = 0; n < 4; n++) {
          int col = n0 + wn + n * 16 + (lane & 15);
          y[(size_t)(roff + grow) * DM + col] = f2bf(acc[m][n][r]);
        }
      }
    }
  }
}

// ---------------- combine: out[t] = sum_k w_k * (y[slot_k] + b2[e_k]) ----------------
__global__ __launch_bounds__(256) void k_combine(const int* __restrict__ topi,
    const float* __restrict__ topw, const int* __restrict__ tslot,
    const unsigned short* __restrict__ y, const float* __restrict__ b2,
    float* __restrict__ out) {
  int t = blockIdx.x, tid = threadIdx.x;
  int s0 = tslot[2 * t], s1 = tslot[2 * t + 1];
  int e0 = topi[2 * t], e1 = topi[2 * t + 1];
  float w0 = topw[2 * t], w1 = topw[2 * t + 1];
  int d = tid * 4;
  uint2 ya = *(const uint2*)(y + (size_t)s0 * DM + d);
  uint2 yb = *(const uint2*)(y + (size_t)s1 * DM + d);
  f32x4 bb0 = *(const f32x4*)(b2 + (size_t)e0 * DM + d);
  f32x4 bb1 = *(const f32x4*)(b2 + (size_t)e1 * DM + d);
  f32x4 r;
  r[0] = w0 * (bf2f((unsigned short)(ya.x & 0xffff)) + bb0[0]) + w1 * (bf2f((unsigned short)(yb.x & 0xffff)) + bb1[0]);
  r[1] = w0 * (bf2f((unsigned short)(ya.x >> 16)) + bb0[1]) + w1 * (bf2f((unsigned short)(yb.x >> 16)) + bb1[1]);
  r[2] = w0 * (bf2f((unsigned short)(ya.y & 0xffff)) + bb0[2]) + w1 * (bf2f((unsigned short)(yb.y & 0xffff)) + bb1[2]);
  r[3] = w0 * (bf2f((unsigned short)(ya.y >> 16)) + bb0[3]) + w1 * (bf2f((unsigned short)(yb.y >> 16)) + bb1[3]);
  *(f32x4*)(out + (size_t)t * DM + d) = r;
}

extern "C" void kernel_launch(void* const* d_in, const int* in_sizes, int n_in,
                              void* d_out, int out_size, void* d_ws, size_t ws_size,
                              hipStream_t stream) {
  const float* x  = (const float*)d_in[0];
  const float* Wr = (const float*)d_in[1];
  const float* br = (const float*)d_in[2];
  const float* W1 = (const float*)d_in[3];
  const float* b1 = (const float*)d_in[4];
  const float* W2 = (const float*)d_in[5];
  const float* b2 = (const float*)d_in[6];
  float* out = (float*)d_out;

  char* ws = (char*)d_ws;
  int*   counts  = (int*)(ws + 0);
  int*   cursor  = (int*)(ws + 64);
  int*   offsets = (int*)(ws + 128);
  int*   topi    = (int*)(ws + 256);
  float* topw    = (float*)(ws + 33024);
  int*   perm    = (int*)(ws + 65792);
  int*   tslot   = (int*)(ws + 98560);
  unsigned short* xc  = (unsigned short*)(ws + 164096);               // 4096x1024 bf16 =  8.4 MB
  unsigned short* hb  = (unsigned short*)(ws + 8552704);              // 8192x4096 bf16 = 67.1 MB
  unsigned short* y   = (unsigned short*)(ws + 75661568);             // 8192x1024 bf16 = 16.8 MB
  unsigned short* W1t = (unsigned short*)(ws + 92438784);             // 8x4096x1024 bf16 = 67.1 MB
  unsigned short* W2t = (unsigned short*)(ws + 159547648);            // 8x1024x4096 bf16 = 67.1 MB

  hipMemsetAsync(ws, 0, 256, stream);  // counts, cursor

  k_cvtx<<<T_TOK * DM / (256 * 8), 256, 0, stream>>>(x, xc);
  k_cvtT<<<dim3(DF / 64, DM / 64, NE), 256, 0, stream>>>(W1, W1t, DM, DF);
  k_cvtT<<<dim3(DM / 64, DF / 64, NE), 256, 0, stream>>>(W2, W2t, DF, DM);
  k_router<<<T_TOK, 256, 0, stream>>>(x, Wr, br, topi, topw, counts);
  k_scan<<<1, 64, 0, stream>>>(counts, offsets, out + (size_t)T_TOK * DM);
  k_scatter<<<16, 256, 0, stream>>>(topi, offsets, cursor, perm, tslot);
  k_gemm1<<<dim3(32, 32, 8), 256, 0, stream>>>(xc, W1t, b1, offsets, perm, hb);
  k_gemm2<<<dim3(8, 32, 8), 256, 0, stream>>>(hb, W2t, offsets, y);
  k_combine<<<T_TOK, 256, 0, stream>>>(topi, topw, tslot, y, b2, out);
}